// Round 4
// baseline (125.473 us; speedup 1.0000x reference)
//
#include <hip/hip_runtime.h>

#define NS 1024
#define KD 256
#define H  256
#define NBLK 256   // pair grid 16x16

// rotated LDS word index for a 64x64 tile: conflict-free transpose-write AND
// conflict-free b128 row-reads. word(hh,j) = hh*64 + ((j + 4*(hh>>2)) & 63)
__device__ __forceinline__ int ldsw(int hh, int j) {
    return (hh << 6) + ((j + ((hh >> 2) << 2)) & 63);
}

// ---------------------------------------------------------------------------
// proj: PXW[j][h'] = (x_j . W1col)*w2, PYW[i][h'] = (y_i . W1col + b1)*w2,
// with h' = sign-partitioned permutation of h (w2>=0 first, stable).
// grid (4, 32, 2), block 256.
// ---------------------------------------------------------------------------
__global__ __launch_bounds__(256) void proj_kernel(
    const float* __restrict__ X, const float* __restrict__ Y,
    const float* __restrict__ W1, const float* __restrict__ b1,
    const float* __restrict__ W2,
    float* __restrict__ PXW, float* __restrict__ PYW, int* __restrict__ counter)
{
    if (blockIdx.x == 0 && blockIdx.y == 0 && blockIdx.z == 0 && threadIdx.x == 0)
        *counter = 0;   // pair runs after proj on the stream

    __shared__ float xs[KD][34];   // transposed [k][i-local]
    __shared__ int dsts[H];        // h -> permuted position
    __shared__ int woff[4];

    const int tid = threadIdx.x;

    // per-block sign-partition permutation of W2 (positives first, stable)
    {
        const float w = W2[tid];
        const bool pos = (w >= 0.0f);
        const unsigned long long m = __ballot(pos);
        const int lane = tid & 63, wv = tid >> 6;
        const int below = __popcll(m & ((1ull << lane) - 1ull));
        if (lane == 0) woff[wv] = __popcll(m);
        __syncthreads();
        const int npos = woff[0] + woff[1] + woff[2] + woff[3];
        int posbase = 0;
        #pragma unroll
        for (int q = 0; q < 4; ++q) if (q < wv) posbase += woff[q];
        const int negbase = npos + (wv * 64 - posbase);
        dsts[tid] = pos ? (posbase + below) : (negbase + (lane - below));
    }

    const int z = blockIdx.z;
    const float* __restrict__ A = z ? Y : X;
    const float* __restrict__ W = W1 + (z ? KD * H : 0);
    float* __restrict__ OUT = z ? PYW : PXW;

    const int tx = tid & 15, ty = tid >> 4;
    const int i0 = blockIdx.y * 32, h0 = blockIdx.x * 64;

    // stage x rows transposed (once)
    {
        const int ii = tid & 31, q = tid >> 5;
        #pragma unroll
        for (int u = 0; u < 8; ++u) {
            const int k = u * 32 + q * 4;
            float4 v = *(const float4*)&A[(i0 + ii) * KD + k];
            xs[k + 0][ii] = v.x; xs[k + 1][ii] = v.y;
            xs[k + 2][ii] = v.z; xs[k + 3][ii] = v.w;
        }
    }
    __syncthreads();   // also publishes dsts[]

    float acc[2][4] = {};
    const float* __restrict__ wp = &W[h0 + tx * 4];
    #pragma unroll 8
    for (int k = 0; k < KD; ++k) {
        float4 w4 = *(const float4*)&wp[k * H];
        const float x0 = xs[k][ty * 2 + 0];
        const float x1 = xs[k][ty * 2 + 1];
        acc[0][0] = fmaf(x0, w4.x, acc[0][0]);
        acc[0][1] = fmaf(x0, w4.y, acc[0][1]);
        acc[0][2] = fmaf(x0, w4.z, acc[0][2]);
        acc[0][3] = fmaf(x0, w4.w, acc[0][3]);
        acc[1][0] = fmaf(x1, w4.x, acc[1][0]);
        acc[1][1] = fmaf(x1, w4.y, acc[1][1]);
        acc[1][2] = fmaf(x1, w4.z, acc[1][2]);
        acc[1][3] = fmaf(x1, w4.w, acc[1][3]);
    }

    float bv[4] = {0.f, 0.f, 0.f, 0.f};
    if (z) *(float4*)bv = *(const float4*)&b1[h0 + tx * 4];
    float wv4[4];
    *(float4*)wv4 = *(const float4*)&W2[h0 + tx * 4];
    int d4[4];
    *(int4*)d4 = *(const int4*)&dsts[h0 + tx * 4];

    #pragma unroll
    for (int r = 0; r < 2; ++r) {
        const int row = i0 + ty * 2 + r;
        #pragma unroll
        for (int c = 0; c < 4; ++c)
            OUT[row * H + d4[c]] = (acc[r][c] + bv[c]) * wv4[c];
    }
}

// ---------------------------------------------------------------------------
// pair: 64x64 (i,j) tiles, R4C4/thread. u = pyw_i + pxw_j; accP/accN += |u|
// split at the sign boundary Npos (uniform branch). t1 = 0.5(A + G + F) + c0.
// F/G row-sums accumulated from the staged LDS tiles (fused). Last block
// reduces partials -> out. grid (16,16), block 256.
// ---------------------------------------------------------------------------
__global__ __launch_bounds__(256) void pair_kernel(
    const float* __restrict__ PXW, const float* __restrict__ PYW,
    const float* __restrict__ W2, const float* __restrict__ b2,
    float* __restrict__ eparts, float* __restrict__ dparts,
    int* __restrict__ counter, float* __restrict__ out)
{
    __shared__ float pxt[2][64 * 64];  // 16 KB each
    __shared__ float pyt[2][64 * 64];
    __shared__ float fpx[4 * 64], fpy[4 * 64];
    __shared__ float red_e[256], red_d[256];
    __shared__ double sde[256], sdd[256];
    __shared__ int wcnt[4];
    __shared__ int lastflag;

    const int tid = threadIdx.x;
    const int tx = tid & 15, ty = tid >> 4;
    const int j0 = blockIdx.x * 64, i0 = blockIdx.y * 64;

    // Npos via ballot (published by the prologue barrier)
    {
        const float w = W2[tid];
        const unsigned long long m = __ballot(w >= 0.0f);
        if ((tid & 63) == 0) wcnt[tid >> 6] = __popcll(m);
    }

    const int su = tid & 15, jb = tid >> 4;   // staging: 16 lanes cover 64 h bytes-contig
    float4 sx[4], sy[4];

#define GLOAD(T)                                                              \
    {                                                                         \
        const int hb = (T) * 64;                                              \
        _Pragma("unroll")                                                     \
        for (int t = 0; t < 4; ++t) {                                         \
            sx[t] = *(const float4*)&PXW[(j0 + jb + 16 * t) * H + hb + su * 4];\
            sy[t] = *(const float4*)&PYW[(i0 + jb + 16 * t) * H + hb + su * 4];\
        }                                                                     \
    }

#define SWRITE(B)                                                             \
    {                                                                         \
        _Pragma("unroll")                                                     \
        for (int t = 0; t < 4; ++t) {                                         \
            const int j = jb + 16 * t;                                        \
            pxt[B][ldsw(su * 4 + 0, j)] = sx[t].x;                            \
            pxt[B][ldsw(su * 4 + 1, j)] = sx[t].y;                            \
            pxt[B][ldsw(su * 4 + 2, j)] = sx[t].z;                            \
            pxt[B][ldsw(su * 4 + 3, j)] = sx[t].w;                            \
            pyt[B][ldsw(su * 4 + 0, j)] = sy[t].x;                            \
            pyt[B][ldsw(su * 4 + 1, j)] = sy[t].y;                            \
            pyt[B][ldsw(su * 4 + 2, j)] = sy[t].z;                            \
            pyt[B][ldsw(su * 4 + 3, j)] = sy[t].w;                            \
        }                                                                     \
    }

    GLOAD(0);
    SWRITE(0);
    __syncthreads();
    const int Npos = wcnt[0] + wcnt[1] + wcnt[2] + wcnt[3];

    float accP[4][4] = {}, accN[4][4] = {};
    float fx = 0.f, fy = 0.f;
    const int fj = tid & 63, fq = tid >> 6;

    for (int T = 0; T < 4; ++T) {
        const int cur = T & 1;
        if (T < 3) GLOAD(T + 1);
        const int hb = T * 64;

        #pragma unroll
        for (int g = 0; g < 16; ++g) {
            const int rot = (g << 2);
            const float* bx = &pxt[cur][(g << 8) + ((tx * 4 + rot) & 63)];
            const float* by = &pyt[cur][(g << 8) + ((ty * 4 + rot) & 63)];
            #pragma unroll
            for (int k = 0; k < 4; ++k) {
                float px4[4], py4[4];
                *(float4*)px4 = *(const float4*)&bx[k * 64];
                *(float4*)py4 = *(const float4*)&by[k * 64];
                if (hb + (g << 2) + k < Npos) {   // uniform scalar branch
                    #pragma unroll
                    for (int r = 0; r < 4; ++r)
                        #pragma unroll
                        for (int c = 0; c < 4; ++c)
                            accP[r][c] += fabsf(py4[r] + px4[c]);
                } else {
                    #pragma unroll
                    for (int r = 0; r < 4; ++r)
                        #pragma unroll
                        for (int c = 0; c < 4; ++c)
                            accN[r][c] += fabsf(py4[r] + px4[c]);
                }
            }
        }

        // F/G partial row-sums from the staged tile (before overwrite)
        #pragma unroll
        for (int s = 0; s < 16; ++s) {
            const int hh = fq * 16 + s;
            fx += pxt[cur][ldsw(hh, fj)];
            fy += pyt[cur][ldsw(hh, fj)];
        }

        if (T < 3) SWRITE((T + 1) & 1);
        __syncthreads();
    }

    fpx[fq * 64 + fj] = fx;
    fpy[fq * 64 + fj] = fy;
    __syncthreads();

    // epilogue
    const float c0 = b2[0] - 1.0f;
    float ffe[4], gge[4];
    #pragma unroll
    for (int c = 0; c < 4; ++c) {
        const int j = tx * 4 + c;
        ffe[c] = 0.5f * (fpx[j] + fpx[64 + j] + fpx[128 + j] + fpx[192 + j]);
    }
    #pragma unroll
    for (int r = 0; r < 4; ++r) {
        const int i = ty * 4 + r;
        gge[r] = 0.5f * (fpy[i] + fpy[64 + i] + fpy[128 + i] + fpy[192 + i]) + c0;
    }

    float esum = 0.f, dsum = 0.f;
    #pragma unroll
    for (int r = 0; r < 4; ++r)
        #pragma unroll
        for (int c = 0; c < 4; ++c) {
            const float A = accP[r][c] - accN[r][c];
            const float t1 = fmaf(0.5f, A, gge[r] + ffe[c]);
            esum += expf(t1);
            if (i0 + ty * 4 + r == j0 + tx * 4 + c) dsum += t1 + 1.0f;
        }

    red_e[tid] = esum;
    red_d[tid] = dsum;
    __syncthreads();
    for (int s = 128; s > 0; s >>= 1) {
        if (tid < s) {
            red_e[tid] += red_e[tid + s];
            red_d[tid] += red_d[tid + s];
        }
        __syncthreads();
    }

    const int bid = blockIdx.y * gridDim.x + blockIdx.x;
    if (tid == 0) {
        __hip_atomic_store(&eparts[bid], red_e[0], __ATOMIC_RELAXED, __HIP_MEMORY_SCOPE_AGENT);
        __hip_atomic_store(&dparts[bid], red_d[0], __ATOMIC_RELAXED, __HIP_MEMORY_SCOPE_AGENT);
        __threadfence();
        const int prev = __hip_atomic_fetch_add(counter, 1, __ATOMIC_ACQ_REL, __HIP_MEMORY_SCOPE_AGENT);
        lastflag = (prev == NBLK - 1);
    }
    __syncthreads();

    if (lastflag) {
        __threadfence();
        sde[tid] = (double)__hip_atomic_load(&eparts[tid], __ATOMIC_RELAXED, __HIP_MEMORY_SCOPE_AGENT);
        sdd[tid] = (double)__hip_atomic_load(&dparts[tid], __ATOMIC_RELAXED, __HIP_MEMORY_SCOPE_AGENT);
        __syncthreads();
        for (int s = 128; s > 0; s >>= 1) {
            if (tid < s) { sde[tid] += sde[tid + s]; sdd[tid] += sdd[tid + s]; }
            __syncthreads();
        }
        if (tid == 0)
            out[0] = (float)(sdd[0] / (double)NS - sde[0] / ((double)NS * (double)NS));
    }
#undef GLOAD
#undef SWRITE
}

// ---------------------------------------------------------------------------
extern "C" void kernel_launch(void* const* d_in, const int* in_sizes, int n_in,
                              void* d_out, int out_size, void* d_ws, size_t ws_size,
                              hipStream_t stream)
{
    const float* X  = (const float*)d_in[0];
    const float* Y  = (const float*)d_in[1];
    const float* W1 = (const float*)d_in[2];
    const float* b1 = (const float*)d_in[3];
    const float* W2 = (const float*)d_in[4];
    const float* b2 = (const float*)d_in[5];
    float* out = (float*)d_out;

    float* PXW    = (float*)d_ws;            // [NS][H] permuted+scaled
    float* PYW    = PXW + NS * H;            // [NS][H]
    float* eparts = PYW + NS * H;            // [256]
    float* dparts = eparts + 256;            // [256]
    int*   counter = (int*)(dparts + 256);

    proj_kernel<<<dim3(4, 32, 2), 256, 0, stream>>>(X, Y, W1, b1, W2, PXW, PYW, counter);
    pair_kernel<<<dim3(16, 16), 256, 0, stream>>>(PXW, PYW, W2, b2, eparts, dparts, counter, out);
}